// Round 4
// baseline (271.150 us; speedup 1.0000x reference)
//
#include <hip/hip_runtime.h>
#include <stdint.h>

// L2 1-NN, B=4096 x[B,256] vs N=32768 P[N,256] fp32.
// Round 4: N-sweep bf16 MFMA screen — A-in-registers (K=256 fits!), B streamed
// through a counted-vmcnt double-buffered LDS pipeline (raw s_barrier, never
// drain vmcnt to 0 mid-loop). 64-col-group u32 blockmin + fp32 margin rescore.
// argmin_j (psq[j] - 2 x.p_j); x_sq drops out. Candidate set
// {64-col groups with approx groupmin <= approx_min + MARGIN} provably
// contains the exact argmin (MARGIN >= 2*max bf16 screening error ~0.8).

#define NB 4096
#define NP 32768
#define ND 256
#define NG 512             // N / 64 column groups
#define MARGIN 2.0f

#define NSPLIT 8           // N-splits (one per XCD)
#define CPB    4096        // cols per block (NP / NSPLIT)
#define NCT    16          // 256-col tiles per block
#define NITER  32          // NCT * 2 K-halves

typedef __attribute__((ext_vector_type(8))) __bf16 bf16x8;
typedef __attribute__((ext_vector_type(4))) __bf16 bf16x4;
typedef __attribute__((ext_vector_type(4))) float f32x4;

// ---- workspace layout (bytes) ----
static constexpr size_t OFF_PSQ = 0;                               // 32768 f32
static constexpr size_t OFF_XB  = 131072;                          // 4096x256 bf16
static constexpr size_t OFF_PB  = OFF_XB + (size_t)NB * ND * 2;    // 32768x256 bf16
static constexpr size_t OFF_BM  = OFF_PB + (size_t)NP * ND * 2;    // 4096x512 u32
static constexpr size_t WS_NEED = OFF_BM + (size_t)NB * NG * 4;    // 27,394,048

__device__ __forceinline__ void gload_lds16(const void* g, void* l) {
    __builtin_amdgcn_global_load_lds(
        (const __attribute__((address_space(1))) uint32_t*)g,
        (__attribute__((address_space(3))) uint32_t*)l, 16, 0, 0);
}
__device__ __forceinline__ unsigned fkey(float f) {
    unsigned u = __float_as_uint(f);
    return (u & 0x80000000u) ? ~u : (u | 0x80000000u);
}
__device__ __forceinline__ float fkey_inv(unsigned u) {
    unsigned o = (u & 0x80000000u) ? (u & 0x7FFFFFFFu) : ~u;
    return __uint_as_float(o);
}
__device__ __forceinline__ unsigned long long umin64(unsigned long long a,
                                                     unsigned long long b) {
    return a < b ? a : b;
}
__device__ __forceinline__ unsigned umin32(unsigned a, unsigned b) {
    return a < b ? a : b;
}

// ------------------------------------------------- prep: bf16 convert + psq
__global__ void prep_kernel(const float* __restrict__ X, const float* __restrict__ P,
                            float* __restrict__ psq, __bf16* __restrict__ Xb,
                            __bf16* __restrict__ Pb) {
    int row  = blockIdx.x * 4 + (threadIdx.x >> 6);  // one wave per row
    int lane = threadIdx.x & 63;
    if (row < NP) {
        f32x4 v = ((const f32x4*)(P + (size_t)row * ND))[lane];
        bf16x4 b;
        b.x = (__bf16)v.x; b.y = (__bf16)v.y; b.z = (__bf16)v.z; b.w = (__bf16)v.w;
        ((bf16x4*)(Pb + (size_t)row * ND))[lane] = b;
        float s = v.x*v.x + v.y*v.y + v.z*v.z + v.w*v.w;
        #pragma unroll
        for (int off = 32; off > 0; off >>= 1) s += __shfl_down(s, off);
        if (lane == 0) psq[row] = s;
    } else {
        int r = row - NP;   // < NB
        f32x4 v = ((const f32x4*)(X + (size_t)r * ND))[lane];
        bf16x4 b;
        b.x = (__bf16)v.x; b.y = (__bf16)v.y; b.z = (__bf16)v.z; b.w = (__bf16)v.w;
        ((bf16x4*)(Xb + (size_t)r * ND))[lane] = b;
    }
}

// ------------------------- N-sweep MFMA kernel: A in regs, B streamed --------
// Block: 512 thr = 8 waves (2 wm x 4 wn). Block tile M=128; per N-iter 256 cols
// x 128 K (kh halves). Wave tile 64 rows x 64 cols; acc completes every 2 iters.
// LDS: B dbuf 2 x 64KB, lane-linear 16B chunks c = fn*256 + ks*64 + (kg*16+fr)
// (proven 0 bank conflicts in rounds 2-3). Pipeline: stage(t+2) issued after
// the read-release barrier; top-of-iter waits vmcnt(8) (counted, not 0).
__global__ __launch_bounds__(512, 2)
void nn_sweep_kernel(const __bf16* __restrict__ Xb, const __bf16* __restrict__ Pb,
                     const float* __restrict__ psq, unsigned* __restrict__ blockmin) {
    __shared__ __align__(16) char Bs[2][65536];

    const int tid  = threadIdx.x;
    const int lane = tid & 63;
    const int wave = tid >> 6;
    const int wm = wave >> 2, wn = wave & 3;
    const int bid    = blockIdx.x;
    const int mblk   = bid >> 3;
    const int nsplit = bid & 7;          // bid%8 -> same XCD shares B-panel
    const int bm     = mblk * 128;
    const int nbase0 = nsplit * CPB;
    const int fr = lane & 15, kg = lane >> 4;

    // ---- A in registers: this wave's 64 rows x full K=256 ----
    bf16x8 a[4][8];
    #pragma unroll
    for (int mi = 0; mi < 4; ++mi)
        #pragma unroll
        for (int ks = 0; ks < 8; ++ks)
            a[mi][ks] = *(const bf16x8*)(Xb +
                (size_t)(bm + wm * 64 + mi * 16 + fr) * ND + ks * 32 + kg * 8);
    __builtin_amdgcn_sched_barrier(0);

    f32x4 acc[4][4];
    #pragma unroll
    for (int i = 0; i < 4; ++i)
        #pragma unroll
        for (int j = 0; j < 4; ++j) acc[i][j] = (f32x4){0.f, 0.f, 0.f, 0.f};

    const int wbase = tid & ~63;

    // stage one (ct, kh) B-tile: 256 cols x 128 K = 64KB, 8 x 16B per thread
    auto stage = [&](int ct, int kh, char* buf) {
        const int nbase = nbase0 + ct * 256;
        #pragma unroll
        for (int i = 0; i < 8; ++i) {
            const int c   = i * 512 + tid;       // chunk 0..4095
            const int fn  = c >> 8;
            const int ks  = (c >> 6) & 3;
            const int l   = c & 63;
            const int lkg = l >> 4, lfr = l & 15;
            gload_lds16(Pb + (size_t)(nbase + fn * 16 + lfr) * ND +
                            (kh * 4 + ks) * 32 + lkg * 8,
                        buf + (size_t)(i * 512 + wbase) * 16);
        }
    };

    stage(0, 0, (char*)Bs[0]);
    __builtin_amdgcn_sched_barrier(0);
    stage(0, 1, (char*)Bs[1]);
    __builtin_amdgcn_sched_barrier(0);

    for (int ct = 0; ct < NCT; ++ct) {
        #pragma unroll
        for (int kh = 0; kh < 2; ++kh) {
            const int t = ct * 2 + kh;
            if (t < NITER - 1) asm volatile("s_waitcnt vmcnt(8)" ::: "memory");
            else               asm volatile("s_waitcnt vmcnt(0)" ::: "memory");
            __builtin_amdgcn_sched_barrier(0);
            __builtin_amdgcn_s_barrier();
            __builtin_amdgcn_sched_barrier(0);

            const char* buf = (const char*)Bs[t & 1];
            #pragma unroll
            for (int ks = 0; ks < 4; ++ks) {
                bf16x8 b[4];
                #pragma unroll
                for (int ni = 0; ni < 4; ++ni)
                    b[ni] = *(const bf16x8*)(buf +
                        (size_t)((((wn * 4 + ni) * 4 + ks) * 64 + lane)) * 16);
                #pragma unroll
                for (int mi = 0; mi < 4; ++mi)
                    #pragma unroll
                    for (int ni = 0; ni < 4; ++ni)
                        acc[mi][ni] = __builtin_amdgcn_mfma_f32_16x16x32_bf16(
                            a[mi][kh * 4 + ks], b[ni], acc[mi][ni], 0, 0, 0);
            }

            if (kh == 1) {
                // epilogue: this wave alone covers 64 consecutive cols -> one
                // 64-col group per ct: g = nsplit*64 + ct*4 + wn. Direct store.
                const int colb = nbase0 + ct * 256 + wn * 64;
                float cq[4];
                #pragma unroll
                for (int ni = 0; ni < 4; ++ni) cq[ni] = psq[colb + ni * 16 + fr];
                const int g = nsplit * 64 + ct * 4 + wn;
                #pragma unroll
                for (int mi = 0; mi < 4; ++mi) {
                    #pragma unroll
                    for (int r = 0; r < 4; ++r) {
                        float d = fmaf(-2.f, acc[mi][0][r], cq[0]);
                        #pragma unroll
                        for (int ni = 1; ni < 4; ++ni)
                            d = fminf(d, fmaf(-2.f, acc[mi][ni][r], cq[ni]));
                        #pragma unroll
                        for (int m = 1; m < 16; m <<= 1)
                            d = fminf(d, __shfl_xor(d, m));
                        if (fr == 0)
                            blockmin[(size_t)(bm + wm * 64 + mi * 16 + kg * 4 + r)
                                     * NG + g] = fkey(d);
                    }
                }
                #pragma unroll
                for (int i = 0; i < 4; ++i)
                    #pragma unroll
                    for (int j = 0; j < 4; ++j)
                        acc[i][j] = (f32x4){0.f, 0.f, 0.f, 0.f};
            }

            asm volatile("s_waitcnt lgkmcnt(0)" ::: "memory");
            __builtin_amdgcn_sched_barrier(0);
            __builtin_amdgcn_s_barrier();
            __builtin_amdgcn_sched_barrier(0);
            const int t2 = t + 2;
            if (t2 < NITER) stage(t2 >> 1, t2 & 1, (char*)Bs[t & 1]);
        }
    }
}

// ------------- per-row: approx min -> candidate 64-col groups -> fp32 rescore
__global__ __launch_bounds__(256)
void rescore_kernel(const float* __restrict__ X, const float* __restrict__ P,
                    const float* __restrict__ psq,
                    const unsigned* __restrict__ blockmin,
                    float* __restrict__ out) {
    __shared__ float Xs[256];
    __shared__ float part[256];
    __shared__ unsigned keymin[256];
    __shared__ unsigned short cand[NG];
    __shared__ int cnt;
    __shared__ unsigned bcol_s;

    const int row = blockIdx.x;
    const int tid = threadIdx.x;
    const unsigned* bmr = blockmin + (size_t)row * NG;

    unsigned k0 = bmr[tid], k1 = bmr[tid + 256];
    if (tid < 64)
        ((f32x4*)Xs)[tid] = ((const f32x4*)(X + (size_t)row * ND))[tid];
    if (tid == 0) cnt = 0;
    keymin[tid] = umin32(k0, k1);
    __syncthreads();
    #pragma unroll
    for (int s = 128; s > 0; s >>= 1) {
        if (tid < s) keymin[tid] = umin32(keymin[tid], keymin[tid + s]);
        __syncthreads();
    }
    unsigned thr = fkey(fkey_inv(keymin[0]) + MARGIN);
    if (k0 <= thr) cand[atomicAdd(&cnt, 1)] = (unsigned short)tid;
    if (k1 <= thr) cand[atomicAdd(&cnt, 1)] = (unsigned short)(tid + 256);
    __syncthreads();

    const int n     = cnt;
    const int ct    = tid & 63;     // col within group
    const int cpart = tid >> 6;     // k-quarter (64 dims)
    unsigned long long best = 0xFFFFFFFFFFFFFFFFull;
    for (int c = 0; c < n; ++c) {
        int g = cand[c];
        int col = g * 64 + ct;
        const f32x4* p4 = (const f32x4*)(P + (size_t)col * ND + cpart * 64);
        const f32x4* x4 = (const f32x4*)(Xs + cpart * 64);
        float s = 0.f;
        #pragma unroll
        for (int i = 0; i < 16; ++i) {
            f32x4 pv = p4[i], xv = x4[i];
            s = fmaf(xv.x, pv.x, s); s = fmaf(xv.y, pv.y, s);
            s = fmaf(xv.z, pv.z, s); s = fmaf(xv.w, pv.w, s);
        }
        part[tid] = s;
        __syncthreads();
        if (tid < 64) {
            int col2 = g * 64 + tid;
            float tot = part[tid] + part[tid + 64] + part[tid + 128] + part[tid + 192];
            float d = fmaf(-2.f, tot, psq[col2]);
            best = umin64(best, ((unsigned long long)fkey(d) << 32) |
                                (unsigned long long)col2);
        }
        __syncthreads();
    }
    if (tid < 64) {
        #pragma unroll
        for (int m = 1; m < 64; m <<= 1)
            best = umin64(best, __shfl_xor(best, m));
        if (tid == 0) bcol_s = (unsigned)(best & 0xFFFFFFFFull);
    }
    __syncthreads();
    unsigned bc = bcol_s;
    if (tid < 64)
        ((f32x4*)(out + (size_t)row * ND))[tid] =
            ((const f32x4*)(P + (size_t)bc * ND))[tid];
}

// ======================= fallback: exact fp32 path (small ws) ===============
#define BM1 128
#define BN1 128
#define BK1 32
#define LDA1 132

__global__ void psq_init_kernel(const float* __restrict__ P, float* __restrict__ psq,
                                unsigned long long* __restrict__ minpack) {
    int row  = blockIdx.x * 4 + (threadIdx.x >> 6);
    int lane = threadIdx.x & 63;
    float4 p4 = ((const float4*)(P + (size_t)row * ND))[lane];
    float s = p4.x*p4.x + p4.y*p4.y + p4.z*p4.z + p4.w*p4.w;
    #pragma unroll
    for (int off = 32; off > 0; off >>= 1) s += __shfl_down(s, off);
    if (lane == 0) psq[row] = s;
    int gid = blockIdx.x * blockDim.x + threadIdx.x;
    if (gid < NB) minpack[gid] = 0xFFFFFFFFFFFFFFFFull;
}

__global__ __launch_bounds__(256, 2)
void nn_main_kernel(const float* __restrict__ X, const float* __restrict__ P,
                    const float* __restrict__ psq,
                    unsigned long long* __restrict__ minpack) {
    __shared__ __align__(16) char smem_raw[2 * BK1 * LDA1 * 4];
    float (*As)[LDA1] = (float (*)[LDA1])smem_raw;
    float (*Bs)[LDA1] = (float (*)[LDA1])(smem_raw + BK1 * LDA1 * 4);
    const int bm  = blockIdx.y * BM1;
    const int bn  = blockIdx.x * BN1;
    const int tid = threadIdx.x;
    const int tx  = tid & 15;
    const int ty  = tid >> 4;
    float acc[8][8];
    #pragma unroll
    for (int i = 0; i < 8; ++i)
        #pragma unroll
        for (int j = 0; j < 8; ++j) acc[i][j] = 0.f;
    const int lrow = tid >> 3;
    const int lk   = (tid & 7) * 4;
    for (int k0 = 0; k0 < ND; k0 += BK1) {
        #pragma unroll
        for (int p = 0; p < 4; ++p) {
            int r = p * 32 + lrow;
            float4 a = *(const float4*)(X + (size_t)(bm + r) * ND + k0 + lk);
            As[lk+0][r] = a.x; As[lk+1][r] = a.y; As[lk+2][r] = a.z; As[lk+3][r] = a.w;
            float4 b = *(const float4*)(P + (size_t)(bn + r) * ND + k0 + lk);
            Bs[lk+0][r] = b.x; Bs[lk+1][r] = b.y; Bs[lk+2][r] = b.z; Bs[lk+3][r] = b.w;
        }
        __syncthreads();
        #pragma unroll 4
        for (int k = 0; k < BK1; ++k) {
            float4 a0 = *(const float4*)&As[k][ty*8];
            float4 a1 = *(const float4*)&As[k][ty*8 + 4];
            float4 b0 = *(const float4*)&Bs[k][tx*4];
            float4 b1 = *(const float4*)&Bs[k][64 + tx*4];
            float av[8] = {a0.x,a0.y,a0.z,a0.w,a1.x,a1.y,a1.z,a1.w};
            float bv[8] = {b0.x,b0.y,b0.z,b0.w,b1.x,b1.y,b1.z,b1.w};
            #pragma unroll
            for (int i = 0; i < 8; ++i)
                #pragma unroll
                for (int j = 0; j < 8; ++j)
                    acc[i][j] = fmaf(av[i], bv[j], acc[i][j]);
        }
        __syncthreads();
    }
    unsigned long long (*red)[16] = (unsigned long long (*)[16])smem_raw;
    float cj[8];
    int   jglob[8];
    #pragma unroll
    for (int j = 0; j < 8; ++j) {
        int c = (j < 4) ? (tx*4 + j) : (64 + tx*4 + (j - 4));
        jglob[j] = bn + c;
        cj[j]    = psq[bn + c];
    }
    #pragma unroll
    for (int i = 0; i < 8; ++i) {
        float best = 0.f; unsigned bidx = 0u; bool first = true;
        #pragma unroll
        for (int j = 0; j < 8; ++j) {
            float s = fmaf(-2.f, acc[i][j], cj[j]);
            if (first || s < best) { best = s; bidx = (unsigned)jglob[j]; first = false; }
        }
        unsigned u = fkey(best);
        red[ty*8 + i][tx] = ((unsigned long long)u << 32) | (unsigned long long)bidx;
    }
    __syncthreads();
    if (tid < BM1) {
        unsigned long long m = red[tid][0];
        #pragma unroll
        for (int t = 1; t < 16; ++t) m = umin64(m, red[tid][t]);
        atomicMin(&minpack[bm + tid], m);
    }
}

__global__ void gather_kernel(const float* __restrict__ P,
                              const unsigned long long* __restrict__ minpack,
                              float* __restrict__ out) {
    int row = blockIdx.x;
    unsigned idx = (unsigned)(minpack[row] & 0xFFFFFFFFull);
    int lane = threadIdx.x;
    ((float4*)(out + (size_t)row * ND))[lane] =
        ((const float4*)(P + (size_t)idx * ND))[lane];
}

// ------------------------------------------------------------------- launch
extern "C" void kernel_launch(void* const* d_in, const int* in_sizes, int n_in,
                              void* d_out, int out_size, void* d_ws, size_t ws_size,
                              hipStream_t stream) {
    const float* X = (const float*)d_in[0];
    const float* P = (const float*)d_in[1];
    float* out = (float*)d_out;
    char* w = (char*)d_ws;

    if (ws_size >= WS_NEED) {
        float* psq = (float*)(w + OFF_PSQ);
        __bf16* Xb = (__bf16*)(w + OFF_XB);
        __bf16* Pb = (__bf16*)(w + OFF_PB);
        unsigned* blockmin = (unsigned*)(w + OFF_BM);

        prep_kernel<<<(NP + NB) / 4, 256, 0, stream>>>(X, P, psq, Xb, Pb);
        nn_sweep_kernel<<<(NB / 128) * NSPLIT, 512, 0, stream>>>(Xb, Pb, psq,
                                                                 blockmin);
        rescore_kernel<<<NB, 256, 0, stream>>>(X, P, psq, blockmin, out);
    } else {
        float* psq = (float*)w;
        unsigned long long* minpack = (unsigned long long*)(w + (size_t)NP * 4);
        psq_init_kernel<<<NP / 4, 256, 0, stream>>>(P, psq, minpack);
        dim3 grid(NP / BN1, NB / BM1);
        nn_main_kernel<<<grid, dim3(256), 0, stream>>>(X, P, psq, minpack);
        gather_kernel<<<NB, 64, 0, stream>>>(P, minpack, out);
    }
}

// Round 5
// 198.480 us; speedup vs baseline: 1.3661x; 1.3661x over previous
//
#include <hip/hip_runtime.h>
#include <stdint.h>

// L2 1-NN, B=4096 x[B,256] vs N=32768 P[N,256] fp32.
// Round 5: 256x256 bf16 MFMA screen with the 8-phase piece-staggered schedule
// (m201 template): K-tile LDS split into 4x16KB pieces (A/B x ks-half), one
// piece staged per phase, counted vmcnt(6) at tile p0/p2 (never 0 mid-loop),
// one s_barrier per phase, setprio(1) around each 16-MFMA cluster. Argmin
// epilogue once per block. 64-col-group u32 blockmin + fp32 margin rescore.
// argmin_j (psq[j] - 2 x.p_j); x_sq drops out. Candidate set
// {64-col groups with approx groupmin <= approx_min + MARGIN} provably
// contains the exact argmin (MARGIN >= 2*max bf16 screening error ~0.8).

#define NB 4096
#define NP 32768
#define ND 256
#define NG 512             // N / 64 column groups
#define MARGIN 2.0f

typedef __attribute__((ext_vector_type(8))) __bf16 bf16x8;
typedef __attribute__((ext_vector_type(4))) __bf16 bf16x4;
typedef __attribute__((ext_vector_type(4))) float f32x4;

// ---- workspace layout (bytes) ----
static constexpr size_t OFF_PSQ = 0;                               // 32768 f32
static constexpr size_t OFF_XB  = 131072;                          // 4096x256 bf16
static constexpr size_t OFF_PB  = OFF_XB + (size_t)NB * ND * 2;    // 32768x256 bf16
static constexpr size_t OFF_BM  = OFF_PB + (size_t)NP * ND * 2;    // 4096x512 u32
static constexpr size_t WS_NEED = OFF_BM + (size_t)NB * NG * 4;    // 27,394,048

#define VMCNT(n) asm volatile("s_waitcnt vmcnt(" #n ")" ::: "memory")

__device__ __forceinline__ void gload_lds16(const void* g, void* l) {
    __builtin_amdgcn_global_load_lds(
        (const __attribute__((address_space(1))) uint32_t*)g,
        (__attribute__((address_space(3))) uint32_t*)l, 16, 0, 0);
}
__device__ __forceinline__ unsigned fkey(float f) {
    unsigned u = __float_as_uint(f);
    return (u & 0x80000000u) ? ~u : (u | 0x80000000u);
}
__device__ __forceinline__ float fkey_inv(unsigned u) {
    unsigned o = (u & 0x80000000u) ? (u & 0x7FFFFFFFu) : ~u;
    return __uint_as_float(o);
}
__device__ __forceinline__ unsigned long long umin64(unsigned long long a,
                                                     unsigned long long b) {
    return a < b ? a : b;
}
__device__ __forceinline__ unsigned umin32(unsigned a, unsigned b) {
    return a < b ? a : b;
}

// ------------------------------------------------- prep: bf16 convert + psq
__global__ void prep_kernel(const float* __restrict__ X, const float* __restrict__ P,
                            float* __restrict__ psq, __bf16* __restrict__ Xb,
                            __bf16* __restrict__ Pb) {
    int row  = blockIdx.x * 4 + (threadIdx.x >> 6);  // one wave per row
    int lane = threadIdx.x & 63;
    if (row < NP) {
        f32x4 v = ((const f32x4*)(P + (size_t)row * ND))[lane];
        bf16x4 b;
        b.x = (__bf16)v.x; b.y = (__bf16)v.y; b.z = (__bf16)v.z; b.w = (__bf16)v.w;
        ((bf16x4*)(Pb + (size_t)row * ND))[lane] = b;
        float s = v.x*v.x + v.y*v.y + v.z*v.z + v.w*v.w;
        #pragma unroll
        for (int off = 32; off > 0; off >>= 1) s += __shfl_down(s, off);
        if (lane == 0) psq[row] = s;
    } else {
        int r = row - NP;   // < NB
        f32x4 v = ((const f32x4*)(X + (size_t)r * ND))[lane];
        bf16x4 b;
        b.x = (__bf16)v.x; b.y = (__bf16)v.y; b.z = (__bf16)v.z; b.w = (__bf16)v.w;
        ((bf16x4*)(Xb + (size_t)r * ND))[lane] = b;
    }
}

// -------------------- 8-phase 256x256 MFMA screen kernel --------------------
// 512 thr = 8 waves (wm 0..1 x wn 0..3); wave tile 128 rows x 64 cols,
// acc[8][4] 16x16 fragments. K = 4 tiles of BK=64, each split in ks-halves.
// LDS: A pieces [buf][ks] 4x16KB + B pieces 4x16KB = 128KB. Piece layout:
// lane-linear 16B chunks, chunk = frag*64 + (kg*16 + fr) (0 bank conflicts,
// proven rounds 2-4). Pipeline: piece X(t+1) issued at phase X of tile t;
// vmcnt(6) at p0/p2 = {2 remaining pieces of tile t} + {1 just-issued piece}.
__global__ __launch_bounds__(512, 2)
void nn_8ph_kernel(const __bf16* __restrict__ Xb, const __bf16* __restrict__ Pb,
                   const float* __restrict__ psq, unsigned* __restrict__ blockmin) {
    __shared__ __align__(16) char smem[131072];

    const int tid  = threadIdx.x;
    const int lane = tid & 63;
    const int wave = tid >> 6;
    const int wm = wave >> 2, wn = wave & 3;
    const int bm = blockIdx.x * 256;    // 16 consecutive blocks share B-panel
    const int bn = blockIdx.y * 256;

    f32x4 acc[8][4];
    #pragma unroll
    for (int i = 0; i < 8; ++i)
        #pragma unroll
        for (int j = 0; j < 4; ++j) acc[i][j] = (f32x4){0.f, 0.f, 0.f, 0.f};

    const int wbase16 = (tid & ~63) * 16;   // wave-uniform chunk base (bytes)

    // stage one 16KB piece: 2 x global_load_lds(16B) per thread
    auto stageA = [&](int buf, int ks, int t) {
        char* dst = smem + (size_t)(buf * 2 + ks) * 16384;
        #pragma unroll
        for (int i = 0; i < 2; ++i) {
            const int c  = i * 512 + tid;      // chunk 0..1023
            const int fm = c >> 6;
            const int l  = c & 63;
            gload_lds16(Xb + (size_t)(bm + fm * 16 + (l & 15)) * ND +
                            t * 64 + ks * 32 + (l >> 4) * 8,
                        dst + i * 512 * 16 + wbase16);
        }
    };
    auto stageB = [&](int buf, int ks, int t) {
        char* dst = smem + 65536 + (size_t)(buf * 2 + ks) * 16384;
        #pragma unroll
        for (int i = 0; i < 2; ++i) {
            const int c  = i * 512 + tid;
            const int fn = c >> 6;
            const int l  = c & 63;
            gload_lds16(Pb + (size_t)(bn + fn * 16 + (l & 15)) * ND +
                            t * 64 + ks * 32 + (l >> 4) * 8,
                        dst + i * 512 * 16 + wbase16);
        }
    };

    // prologue: all 4 pieces of tile 0
    stageA(0, 0, 0); stageB(0, 0, 0); stageA(0, 1, 0); stageB(0, 1, 0);

    #pragma unroll
    for (int t = 0; t < 4; ++t) {
        const int b  = t & 1;
        const int nb = b ^ 1;
        const char* Ap0 = smem + (size_t)(b * 2 + 0) * 16384;
        const char* Ap1 = smem + (size_t)(b * 2 + 1) * 16384;
        const char* Bp0 = smem + 65536 + (size_t)(b * 2 + 0) * 16384;
        const char* Bp1 = smem + 65536 + (size_t)(b * 2 + 1) * 16384;

        // ---------------- phase 0: (ks=0, mi 0-3) ----------------
        if (t < 3) stageA(nb, 0, t + 1);
        if (t < 3) { VMCNT(6); } else { VMCNT(4); }
        __builtin_amdgcn_s_barrier();
        __builtin_amdgcn_sched_barrier(0);
        bf16x8 b0[4], a0[4];
        #pragma unroll
        for (int ni = 0; ni < 4; ++ni)
            b0[ni] = *(const bf16x8*)(Bp0 +
                      (size_t)((wn * 4 + ni) * 64 + lane) * 16);
        #pragma unroll
        for (int mi = 0; mi < 4; ++mi)
            a0[mi] = *(const bf16x8*)(Ap0 +
                      (size_t)((wm * 8 + mi) * 64 + lane) * 16);
        __builtin_amdgcn_s_setprio(1);
        #pragma unroll
        for (int mi = 0; mi < 4; ++mi)
            #pragma unroll
            for (int ni = 0; ni < 4; ++ni)
                acc[mi][ni] = __builtin_amdgcn_mfma_f32_16x16x32_bf16(
                    a0[mi], b0[ni], acc[mi][ni], 0, 0, 0);
        __builtin_amdgcn_s_setprio(0);

        // ---------------- phase 1: (ks=0, mi 4-7) ----------------
        if (t < 3) stageB(nb, 0, t + 1);
        __builtin_amdgcn_s_barrier();
        __builtin_amdgcn_sched_barrier(0);
        #pragma unroll
        for (int mi = 0; mi < 4; ++mi)
            a0[mi] = *(const bf16x8*)(Ap0 +
                      (size_t)((wm * 8 + 4 + mi) * 64 + lane) * 16);
        __builtin_amdgcn_s_setprio(1);
        #pragma unroll
        for (int mi = 0; mi < 4; ++mi)
            #pragma unroll
            for (int ni = 0; ni < 4; ++ni)
                acc[4 + mi][ni] = __builtin_amdgcn_mfma_f32_16x16x32_bf16(
                    a0[mi], b0[ni], acc[4 + mi][ni], 0, 0, 0);
        __builtin_amdgcn_s_setprio(0);

        // ---------------- phase 2: (ks=1, mi 0-3) ----------------
        if (t < 3) stageA(nb, 1, t + 1);
        if (t < 3) { VMCNT(6); } else { VMCNT(0); }
        __builtin_amdgcn_s_barrier();
        __builtin_amdgcn_sched_barrier(0);
        #pragma unroll
        for (int ni = 0; ni < 4; ++ni)
            b0[ni] = *(const bf16x8*)(Bp1 +
                      (size_t)((wn * 4 + ni) * 64 + lane) * 16);
        #pragma unroll
        for (int mi = 0; mi < 4; ++mi)
            a0[mi] = *(const bf16x8*)(Ap1 +
                      (size_t)((wm * 8 + mi) * 64 + lane) * 16);
        __builtin_amdgcn_s_setprio(1);
        #pragma unroll
        for (int mi = 0; mi < 4; ++mi)
            #pragma unroll
            for (int ni = 0; ni < 4; ++ni)
                acc[mi][ni] = __builtin_amdgcn_mfma_f32_16x16x32_bf16(
                    a0[mi], b0[ni], acc[mi][ni], 0, 0, 0);
        __builtin_amdgcn_s_setprio(0);

        // ---------------- phase 3: (ks=1, mi 4-7) ----------------
        if (t < 3) stageB(nb, 1, t + 1);
        __builtin_amdgcn_s_barrier();
        __builtin_amdgcn_sched_barrier(0);
        #pragma unroll
        for (int mi = 0; mi < 4; ++mi)
            a0[mi] = *(const bf16x8*)(Ap1 +
                      (size_t)((wm * 8 + 4 + mi) * 64 + lane) * 16);
        __builtin_amdgcn_s_setprio(1);
        #pragma unroll
        for (int mi = 0; mi < 4; ++mi)
            #pragma unroll
            for (int ni = 0; ni < 4; ++ni)
                acc[4 + mi][ni] = __builtin_amdgcn_mfma_f32_16x16x32_bf16(
                    a0[mi], b0[ni], acc[4 + mi][ni], 0, 0, 0);
        __builtin_amdgcn_s_setprio(0);
    }

    // ---- epilogue (once per block): dist = psq - 2*dot; per-wave 64-col min
    const int cl = lane & 15;     // C col within fragment
    const int rg = lane >> 4;     // C row group
    float cq[4];
    #pragma unroll
    for (int ni = 0; ni < 4; ++ni) cq[ni] = psq[bn + wn * 64 + ni * 16 + cl];
    const int gidx = blockIdx.y * 4 + wn;
    #pragma unroll
    for (int mi = 0; mi < 8; ++mi) {
        #pragma unroll
        for (int r = 0; r < 4; ++r) {
            int row = bm + wm * 128 + mi * 16 + rg * 4 + r;
            float best = fmaf(-2.f, acc[mi][0][r], cq[0]);
            #pragma unroll
            for (int ni = 1; ni < 4; ++ni)
                best = fminf(best, fmaf(-2.f, acc[mi][ni][r], cq[ni]));
            #pragma unroll
            for (int m = 1; m < 16; m <<= 1)
                best = fminf(best, __shfl_xor(best, m));
            if (cl == 0) blockmin[(size_t)row * NG + gidx] = fkey(best);
        }
    }
}

// ------------- per-row: approx min -> candidate 64-col groups -> fp32 rescore
__global__ __launch_bounds__(256)
void rescore_kernel(const float* __restrict__ X, const float* __restrict__ P,
                    const float* __restrict__ psq,
                    const unsigned* __restrict__ blockmin,
                    float* __restrict__ out) {
    __shared__ float Xs[256];
    __shared__ float part[256];
    __shared__ unsigned keymin[256];
    __shared__ unsigned short cand[NG];
    __shared__ int cnt;
    __shared__ unsigned bcol_s;

    const int row = blockIdx.x;
    const int tid = threadIdx.x;
    const unsigned* bmr = blockmin + (size_t)row * NG;

    unsigned k0 = bmr[tid], k1 = bmr[tid + 256];
    if (tid < 64)
        ((f32x4*)Xs)[tid] = ((const f32x4*)(X + (size_t)row * ND))[tid];
    if (tid == 0) cnt = 0;
    keymin[tid] = umin32(k0, k1);
    __syncthreads();
    #pragma unroll
    for (int s = 128; s > 0; s >>= 1) {
        if (tid < s) keymin[tid] = umin32(keymin[tid], keymin[tid + s]);
        __syncthreads();
    }
    unsigned thr = fkey(fkey_inv(keymin[0]) + MARGIN);
    if (k0 <= thr) cand[atomicAdd(&cnt, 1)] = (unsigned short)tid;
    if (k1 <= thr) cand[atomicAdd(&cnt, 1)] = (unsigned short)(tid + 256);
    __syncthreads();

    const int n     = cnt;
    const int ct    = tid & 63;     // col within group
    const int cpart = tid >> 6;     // k-quarter (64 dims)
    unsigned long long best = 0xFFFFFFFFFFFFFFFFull;
    for (int c = 0; c < n; ++c) {
        int g = cand[c];
        int col = g * 64 + ct;
        const f32x4* p4 = (const f32x4*)(P + (size_t)col * ND + cpart * 64);
        const f32x4* x4 = (const f32x4*)(Xs + cpart * 64);
        float s = 0.f;
        #pragma unroll
        for (int i = 0; i < 16; ++i) {
            f32x4 pv = p4[i], xv = x4[i];
            s = fmaf(xv.x, pv.x, s); s = fmaf(xv.y, pv.y, s);
            s = fmaf(xv.z, pv.z, s); s = fmaf(xv.w, pv.w, s);
        }
        part[tid] = s;
        __syncthreads();
        if (tid < 64) {
            int col2 = g * 64 + tid;
            float tot = part[tid] + part[tid + 64] + part[tid + 128] + part[tid + 192];
            float d = fmaf(-2.f, tot, psq[col2]);
            best = umin64(best, ((unsigned long long)fkey(d) << 32) |
                                (unsigned long long)col2);
        }
        __syncthreads();
    }
    if (tid < 64) {
        #pragma unroll
        for (int m = 1; m < 64; m <<= 1)
            best = umin64(best, __shfl_xor(best, m));
        if (tid == 0) bcol_s = (unsigned)(best & 0xFFFFFFFFull);
    }
    __syncthreads();
    unsigned bc = bcol_s;
    if (tid < 64)
        ((f32x4*)(out + (size_t)row * ND))[tid] =
            ((const f32x4*)(P + (size_t)bc * ND))[tid];
}

// ======================= fallback: exact fp32 path (small ws) ===============
#define BM1 128
#define BN1 128
#define BK1 32
#define LDA1 132

__global__ void psq_init_kernel(const float* __restrict__ P, float* __restrict__ psq,
                                unsigned long long* __restrict__ minpack) {
    int row  = blockIdx.x * 4 + (threadIdx.x >> 6);
    int lane = threadIdx.x & 63;
    float4 p4 = ((const float4*)(P + (size_t)row * ND))[lane];
    float s = p4.x*p4.x + p4.y*p4.y + p4.z*p4.z + p4.w*p4.w;
    #pragma unroll
    for (int off = 32; off > 0; off >>= 1) s += __shfl_down(s, off);
    if (lane == 0) psq[row] = s;
    int gid = blockIdx.x * blockDim.x + threadIdx.x;
    if (gid < NB) minpack[gid] = 0xFFFFFFFFFFFFFFFFull;
}

__global__ __launch_bounds__(256, 2)
void nn_main_kernel(const float* __restrict__ X, const float* __restrict__ P,
                    const float* __restrict__ psq,
                    unsigned long long* __restrict__ minpack) {
    __shared__ __align__(16) char smem_raw[2 * BK1 * LDA1 * 4];
    float (*As)[LDA1] = (float (*)[LDA1])smem_raw;
    float (*Bs)[LDA1] = (float (*)[LDA1])(smem_raw + BK1 * LDA1 * 4);
    const int bm  = blockIdx.y * BM1;
    const int bn  = blockIdx.x * BN1;
    const int tid = threadIdx.x;
    const int tx  = tid & 15;
    const int ty  = tid >> 4;
    float acc[8][8];
    #pragma unroll
    for (int i = 0; i < 8; ++i)
        #pragma unroll
        for (int j = 0; j < 8; ++j) acc[i][j] = 0.f;
    const int lrow = tid >> 3;
    const int lk   = (tid & 7) * 4;
    for (int k0 = 0; k0 < ND; k0 += BK1) {
        #pragma unroll
        for (int p = 0; p < 4; ++p) {
            int r = p * 32 + lrow;
            float4 a = *(const float4*)(X + (size_t)(bm + r) * ND + k0 + lk);
            As[lk+0][r] = a.x; As[lk+1][r] = a.y; As[lk+2][r] = a.z; As[lk+3][r] = a.w;
            float4 b = *(const float4*)(P + (size_t)(bn + r) * ND + k0 + lk);
            Bs[lk+0][r] = b.x; Bs[lk+1][r] = b.y; Bs[lk+2][r] = b.z; Bs[lk+3][r] = b.w;
        }
        __syncthreads();
        #pragma unroll 4
        for (int k = 0; k < BK1; ++k) {
            float4 a0 = *(const float4*)&As[k][ty*8];
            float4 a1 = *(const float4*)&As[k][ty*8 + 4];
            float4 b0 = *(const float4*)&Bs[k][tx*4];
            float4 b1 = *(const float4*)&Bs[k][64 + tx*4];
            float av[8] = {a0.x,a0.y,a0.z,a0.w,a1.x,a1.y,a1.z,a1.w};
            float bv[8] = {b0.x,b0.y,b0.z,b0.w,b1.x,b1.y,b1.z,b1.w};
            #pragma unroll
            for (int i = 0; i < 8; ++i)
                #pragma unroll
                for (int j = 0; j < 8; ++j)
                    acc[i][j] = fmaf(av[i], bv[j], acc[i][j]);
        }
        __syncthreads();
    }
    unsigned long long (*red)[16] = (unsigned long long (*)[16])smem_raw;
    float cj[8];
    int   jglob[8];
    #pragma unroll
    for (int j = 0; j < 8; ++j) {
        int c = (j < 4) ? (tx*4 + j) : (64 + tx*4 + (j - 4));
        jglob[j] = bn + c;
        cj[j]    = psq[bn + c];
    }
    #pragma unroll
    for (int i = 0; i < 8; ++i) {
        float best = 0.f; unsigned bidx = 0u; bool first = true;
        #pragma unroll
        for (int j = 0; j < 8; ++j) {
            float s = fmaf(-2.f, acc[i][j], cj[j]);
            if (first || s < best) { best = s; bidx = (unsigned)jglob[j]; first = false; }
        }
        unsigned u = fkey(best);
        red[ty*8 + i][tx] = ((unsigned long long)u << 32) | (unsigned long long)bidx;
    }
    __syncthreads();
    if (tid < BM1) {
        unsigned long long m = red[tid][0];
        #pragma unroll
        for (int t = 1; t < 16; ++t) m = umin64(m, red[tid][t]);
        atomicMin(&minpack[bm + tid], m);
    }
}

__global__ void gather_kernel(const float* __restrict__ P,
                              const unsigned long long* __restrict__ minpack,
                              float* __restrict__ out) {
    int row = blockIdx.x;
    unsigned idx = (unsigned)(minpack[row] & 0xFFFFFFFFull);
    int lane = threadIdx.x;
    ((float4*)(out + (size_t)row * ND))[lane] =
        ((const float4*)(P + (size_t)idx * ND))[lane];
}

// ------------------------------------------------------------------- launch
extern "C" void kernel_launch(void* const* d_in, const int* in_sizes, int n_in,
                              void* d_out, int out_size, void* d_ws, size_t ws_size,
                              hipStream_t stream) {
    const float* X = (const float*)d_in[0];
    const float* P = (const float*)d_in[1];
    float* out = (float*)d_out;
    char* w = (char*)d_ws;

    if (ws_size >= WS_NEED) {
        float* psq = (float*)(w + OFF_PSQ);
        __bf16* Xb = (__bf16*)(w + OFF_XB);
        __bf16* Pb = (__bf16*)(w + OFF_PB);
        unsigned* blockmin = (unsigned*)(w + OFF_BM);

        prep_kernel<<<(NP + NB) / 4, 256, 0, stream>>>(X, P, psq, Xb, Pb);
        dim3 grid(NB / 256, NP / 256);   // 16 x 128; x-fast shares B-panel
        nn_8ph_kernel<<<grid, dim3(512), 0, stream>>>(Xb, Pb, psq, blockmin);
        rescore_kernel<<<NB, 256, 0, stream>>>(X, P, psq, blockmin, out);
    } else {
        float* psq = (float*)w;
        unsigned long long* minpack = (unsigned long long*)(w + (size_t)NP * 4);
        psq_init_kernel<<<NP / 4, 256, 0, stream>>>(P, psq, minpack);
        dim3 grid(NP / BN1, NB / BM1);
        nn_main_kernel<<<grid, dim3(256), 0, stream>>>(X, P, psq, minpack);
        gather_kernel<<<NB, 64, 0, stream>>>(P, minpack, out);
    }
}

// Round 6
// 193.500 us; speedup vs baseline: 1.4013x; 1.0257x over previous
//
#include <hip/hip_runtime.h>
#include <stdint.h>

// L2 1-NN, B=4096 x[B,256] vs N=32768 P[N,256] fp32.
// Round 6: N-sweep screen. A-in-registers (K=256 -> 128 VGPR/wave), B streamed
// as 16KB pieces through a 4-slot LDS ring with counted vmcnt(4) (never 0
// mid-loop), 1 barrier/phase, 128 uninterrupted phases/block, grid=256 blocks
// (1/CU, zero restarts). Epilogue is VMEM-free (psq + blockmin table in LDS)
// so the vmcnt counting stays pure; one bulk blockmin store per block.
// argmin_j (psq[j] - 2 x.p_j); x_sq drops out. Candidate set
// {64-col groups with approx groupmin <= approx_min + MARGIN} provably
// contains the exact argmin (MARGIN >= 2*max bf16 screening error ~0.8).

#define NB 4096
#define NP 32768
#define ND 256
#define NG 512             // N / 64 column groups
#define MARGIN 2.0f
#define NSPLIT 8
#define CPB 4096           // cols per block (NP / NSPLIT)

typedef __attribute__((ext_vector_type(8))) __bf16 bf16x8;
typedef __attribute__((ext_vector_type(4))) __bf16 bf16x4;
typedef __attribute__((ext_vector_type(4))) float f32x4;

// ---- workspace layout (bytes) ----
static constexpr size_t OFF_PSQ = 0;                               // 32768 f32
static constexpr size_t OFF_XB  = 131072;                          // 4096x256 bf16
static constexpr size_t OFF_PB  = OFF_XB + (size_t)NB * ND * 2;    // 32768x256 bf16
static constexpr size_t OFF_BM  = OFF_PB + (size_t)NP * ND * 2;    // 4096x512 u32
static constexpr size_t WS_NEED = OFF_BM + (size_t)NB * NG * 4;    // 27,394,048

#define VMCNT(n) asm volatile("s_waitcnt vmcnt(" #n ")" ::: "memory")

__device__ __forceinline__ void gload_lds16(const void* g, void* l) {
    __builtin_amdgcn_global_load_lds(
        (const __attribute__((address_space(1))) uint32_t*)g,
        (__attribute__((address_space(3))) uint32_t*)l, 16, 0, 0);
}
__device__ __forceinline__ unsigned fkey(float f) {
    unsigned u = __float_as_uint(f);
    return (u & 0x80000000u) ? ~u : (u | 0x80000000u);
}
__device__ __forceinline__ float fkey_inv(unsigned u) {
    unsigned o = (u & 0x80000000u) ? (u & 0x7FFFFFFFu) : ~u;
    return __uint_as_float(o);
}
__device__ __forceinline__ unsigned long long umin64(unsigned long long a,
                                                     unsigned long long b) {
    return a < b ? a : b;
}
__device__ __forceinline__ unsigned umin32(unsigned a, unsigned b) {
    return a < b ? a : b;
}

// ------------------------------------------------- prep: bf16 convert + psq
__global__ void prep_kernel(const float* __restrict__ X, const float* __restrict__ P,
                            float* __restrict__ psq, __bf16* __restrict__ Xb,
                            __bf16* __restrict__ Pb) {
    int row  = blockIdx.x * 4 + (threadIdx.x >> 6);  // one wave per row
    int lane = threadIdx.x & 63;
    if (row < NP) {
        f32x4 v = ((const f32x4*)(P + (size_t)row * ND))[lane];
        bf16x4 b;
        b.x = (__bf16)v.x; b.y = (__bf16)v.y; b.z = (__bf16)v.z; b.w = (__bf16)v.w;
        ((bf16x4*)(Pb + (size_t)row * ND))[lane] = b;
        float s = v.x*v.x + v.y*v.y + v.z*v.z + v.w*v.w;
        #pragma unroll
        for (int off = 32; off > 0; off >>= 1) s += __shfl_down(s, off);
        if (lane == 0) psq[row] = s;
    } else {
        int r = row - NP;   // < NB
        f32x4 v = ((const f32x4*)(X + (size_t)r * ND))[lane];
        bf16x4 b;
        b.x = (__bf16)v.x; b.y = (__bf16)v.y; b.z = (__bf16)v.z; b.w = (__bf16)v.w;
        ((bf16x4*)(Xb + (size_t)r * ND))[lane] = b;
    }
}

// --------------------- N-sweep kernel: A in regs, B ring-streamed ----------
// 512 thr = 8 waves (wm 0..1 x wn 0..3). Block tile 128 rows x 256 cols/N-tile,
// 16 N-tiles swept. Wave: 64 rows x 64 cols, acc[4][4]; A a[4][8] (128 VGPR).
// B piece = one (N-tile, 32-k) slab, 256 cols x 32 k = 16KB, lane-linear 16B
// chunks c = fn*64 + (kg*16 + fr) (0 bank conflicts, proven r2-r5).
// Ring: 4 x 16KB slots, slot = piece & 3. Phase p: vmcnt(4) -> barrier ->
// issue piece p+3 -> 4 ds_read_b128 -> 16 MFMA. WAR-safe: slot (p+3)&3 was
// last read in phase p-1, whose ds_reads completed (lgkmcnt before MFMA)
// before any wave passed phase p's barrier; stage is issued after it.
__global__ __launch_bounds__(512, 2)
void nn_sweep8_kernel(const __bf16* __restrict__ Xb, const __bf16* __restrict__ Pb,
                      const float* __restrict__ psq,
                      unsigned* __restrict__ blockmin) {
    __shared__ __align__(16) char smem[114688];
    char*     ring    = smem;                        // 4 x 16KB
    float*    psq_lds = (float*)(smem + 65536);      // 4096 f32 (16KB)
    unsigned* tbl     = (unsigned*)(smem + 81920);   // [128 rows][64 groups] u32

    const int tid  = threadIdx.x;
    const int lane = tid & 63;
    const int wave = tid >> 6;
    const int wm = wave >> 2, wn = wave & 3;
    const int bid    = blockIdx.x;
    const int nsplit = bid & 7;          // round-robin -> XCD-local B panel
    const int mblk   = bid >> 3;
    const int bm     = mblk * 128;
    const int Nb     = nsplit * CPB;
    const int fr = lane & 15, kg = lane >> 4;
    const int wbase16 = (tid & ~63) * 16;

    // ---- A in registers: wave's 64 rows x full K=256 ----
    bf16x8 a[4][8];
    #pragma unroll
    for (int mi = 0; mi < 4; ++mi)
        #pragma unroll
        for (int qq = 0; qq < 8; ++qq)
            a[mi][qq] = *(const bf16x8*)(Xb +
                (size_t)(bm + wm * 64 + mi * 16 + fr) * ND + qq * 32 + kg * 8);

    f32x4 acc[4][4];
    #pragma unroll
    for (int i = 0; i < 4; ++i)
        #pragma unroll
        for (int j = 0; j < 4; ++j) acc[i][j] = (f32x4){0.f, 0.f, 0.f, 0.f};

    // stage piece (n-tile nn, k-slab qq): 2 x 16B per thread -> slot qq&3
    auto stage = [&](int nn, int qq) {
        char* dst = ring + (size_t)(qq & 3) * 16384;
        const int colb = Nb + nn * 256;
        #pragma unroll
        for (int i = 0; i < 2; ++i) {
            const int c = i * 512 + tid;          // chunk 0..1023
            const int fn = c >> 6;
            const int l  = c & 63;
            gload_lds16(Pb + (size_t)(colb + fn * 16 + (l & 15)) * ND +
                            qq * 32 + (l >> 4) * 8,
                        dst + i * 8192 + wbase16);
        }
    };

    // ---- prologue: psq slice (2 loads/thread), then pieces 0,1,2 ----
    gload_lds16((const char*)(psq + Nb) + (size_t)tid * 16,
                (char*)psq_lds + wbase16);
    gload_lds16((const char*)(psq + Nb) + 8192 + (size_t)tid * 16,
                (char*)psq_lds + 8192 + wbase16);
    stage(0, 0); stage(0, 1); stage(0, 2);

    #pragma unroll 1
    for (int n = 0; n < 16; ++n) {
        #pragma unroll
        for (int q = 0; q < 8; ++q) {
            // counted wait: outstanding = pieces p..p+2 (6 loads); drain to 4
            if (q == 6) { if (n == 15) { VMCNT(2); } else { VMCNT(4); } }
            else if (q == 7) { if (n == 15) { VMCNT(0); } else { VMCNT(4); } }
            else { VMCNT(4); }
            __builtin_amdgcn_s_barrier();
            __builtin_amdgcn_sched_barrier(0);

            // issue piece p+3 (skip past the end)
            if (q < 5) {
                stage(n, q + 3);
            } else if (n < 15) {
                stage(n + 1, q - 5);
            }

            const char* pc = ring + (size_t)(q & 3) * 16384;
            bf16x8 b[4];
            #pragma unroll
            for (int ni = 0; ni < 4; ++ni)
                b[ni] = *(const bf16x8*)(pc +
                         (size_t)((wn * 4 + ni) * 64 + lane) * 16);
            __builtin_amdgcn_s_setprio(1);
            #pragma unroll
            for (int mi = 0; mi < 4; ++mi)
                #pragma unroll
                for (int ni = 0; ni < 4; ++ni)
                    acc[mi][ni] = __builtin_amdgcn_mfma_f32_16x16x32_bf16(
                        a[mi][q], b[ni], acc[mi][ni], 0, 0, 0);
            __builtin_amdgcn_s_setprio(0);

            if (q == 7) {
                // ---- per-tile epilogue: LDS-only (keeps vmcnt pure) ----
                float cq[4];
                #pragma unroll
                for (int ni = 0; ni < 4; ++ni)
                    cq[ni] = psq_lds[n * 256 + wn * 64 + ni * 16 + fr];
                #pragma unroll
                for (int mi = 0; mi < 4; ++mi) {
                    #pragma unroll
                    for (int r = 0; r < 4; ++r) {
                        float d = fmaf(-2.f, acc[mi][0][r], cq[0]);
                        #pragma unroll
                        for (int ni = 1; ni < 4; ++ni)
                            d = fminf(d, fmaf(-2.f, acc[mi][ni][r], cq[ni]));
                        #pragma unroll
                        for (int m = 1; m < 16; m <<= 1)
                            d = fminf(d, __shfl_xor(d, m));
                        if (fr == 0)
                            tbl[(wm * 64 + mi * 16 + kg * 4 + r) * 64 +
                                (n * 4 + wn)] = fkey(d);
                    }
                }
                #pragma unroll
                for (int i = 0; i < 4; ++i)
                    #pragma unroll
                    for (int j = 0; j < 4; ++j)
                        acc[i][j] = (f32x4){0.f, 0.f, 0.f, 0.f};
            }
        }
    }

    // ---- flush blockmin table: 8192 u32, 16 per thread, coalesced ----
    __syncthreads();
    const int rl = tid >> 2;             // row_local 0..127
    const int gb = (tid & 3) * 16;       // group base within row
    #pragma unroll
    for (int j = 0; j < 4; ++j) {
        *(uint4*)&blockmin[(size_t)(bm + rl) * NG + nsplit * 64 + gb + j * 4] =
            *(const uint4*)&tbl[rl * 64 + gb + j * 4];
    }
}

// ------------- per-row: approx min -> candidate 64-col groups -> fp32 rescore
__global__ __launch_bounds__(256)
void rescore_kernel(const float* __restrict__ X, const float* __restrict__ P,
                    const float* __restrict__ psq,
                    const unsigned* __restrict__ blockmin,
                    float* __restrict__ out) {
    __shared__ float Xs[256];
    __shared__ float part[256];
    __shared__ unsigned keymin[256];
    __shared__ unsigned short cand[NG];
    __shared__ int cnt;
    __shared__ unsigned bcol_s;

    const int row = blockIdx.x;
    const int tid = threadIdx.x;
    const unsigned* bmr = blockmin + (size_t)row * NG;

    unsigned k0 = bmr[tid], k1 = bmr[tid + 256];
    if (tid < 64)
        ((f32x4*)Xs)[tid] = ((const f32x4*)(X + (size_t)row * ND))[tid];
    if (tid == 0) cnt = 0;
    keymin[tid] = umin32(k0, k1);
    __syncthreads();
    #pragma unroll
    for (int s = 128; s > 0; s >>= 1) {
        if (tid < s) keymin[tid] = umin32(keymin[tid], keymin[tid + s]);
        __syncthreads();
    }
    unsigned thr = fkey(fkey_inv(keymin[0]) + MARGIN);
    if (k0 <= thr) cand[atomicAdd(&cnt, 1)] = (unsigned short)tid;
    if (k1 <= thr) cand[atomicAdd(&cnt, 1)] = (unsigned short)(tid + 256);
    __syncthreads();

    const int n     = cnt;
    const int ct    = tid & 63;     // col within group
    const int cpart = tid >> 6;     // k-quarter (64 dims)
    unsigned long long best = 0xFFFFFFFFFFFFFFFFull;
    for (int c = 0; c < n; ++c) {
        int g = cand[c];
        int col = g * 64 + ct;
        const f32x4* p4 = (const f32x4*)(P + (size_t)col * ND + cpart * 64);
        const f32x4* x4 = (const f32x4*)(Xs + cpart * 64);
        float s = 0.f;
        #pragma unroll
        for (int i = 0; i < 16; ++i) {
            f32x4 pv = p4[i], xv = x4[i];
            s = fmaf(xv.x, pv.x, s); s = fmaf(xv.y, pv.y, s);
            s = fmaf(xv.z, pv.z, s); s = fmaf(xv.w, pv.w, s);
        }
        part[tid] = s;
        __syncthreads();
        if (tid < 64) {
            int col2 = g * 64 + tid;
            float tot = part[tid] + part[tid + 64] + part[tid + 128] + part[tid + 192];
            float d = fmaf(-2.f, tot, psq[col2]);
            best = umin64(best, ((unsigned long long)fkey(d) << 32) |
                                (unsigned long long)col2);
        }
        __syncthreads();
    }
    if (tid < 64) {
        #pragma unroll
        for (int m = 1; m < 64; m <<= 1)
            best = umin64(best, __shfl_xor(best, m));
        if (tid == 0) bcol_s = (unsigned)(best & 0xFFFFFFFFull);
    }
    __syncthreads();
    unsigned bc = bcol_s;
    if (tid < 64)
        ((f32x4*)(out + (size_t)row * ND))[tid] =
            ((const f32x4*)(P + (size_t)bc * ND))[tid];
}

// ======================= fallback: exact fp32 path (small ws) ===============
#define BM1 128
#define BN1 128
#define BK1 32
#define LDA1 132

__global__ void psq_init_kernel(const float* __restrict__ P, float* __restrict__ psq,
                                unsigned long long* __restrict__ minpack) {
    int row  = blockIdx.x * 4 + (threadIdx.x >> 6);
    int lane = threadIdx.x & 63;
    float4 p4 = ((const float4*)(P + (size_t)row * ND))[lane];
    float s = p4.x*p4.x + p4.y*p4.y + p4.z*p4.z + p4.w*p4.w;
    #pragma unroll
    for (int off = 32; off > 0; off >>= 1) s += __shfl_down(s, off);
    if (lane == 0) psq[row] = s;
    int gid = blockIdx.x * blockDim.x + threadIdx.x;
    if (gid < NB) minpack[gid] = 0xFFFFFFFFFFFFFFFFull;
}

__global__ __launch_bounds__(256, 2)
void nn_main_kernel(const float* __restrict__ X, const float* __restrict__ P,
                    const float* __restrict__ psq,
                    unsigned long long* __restrict__ minpack) {
    __shared__ __align__(16) char smem_raw[2 * BK1 * LDA1 * 4];
    float (*As)[LDA1] = (float (*)[LDA1])smem_raw;
    float (*Bs)[LDA1] = (float (*)[LDA1])(smem_raw + BK1 * LDA1 * 4);
    const int bm  = blockIdx.y * BM1;
    const int bn  = blockIdx.x * BN1;
    const int tid = threadIdx.x;
    const int tx  = tid & 15;
    const int ty  = tid >> 4;
    float acc[8][8];
    #pragma unroll
    for (int i = 0; i < 8; ++i)
        #pragma unroll
        for (int j = 0; j < 8; ++j) acc[i][j] = 0.f;
    const int lrow = tid >> 3;
    const int lk   = (tid & 7) * 4;
    for (int k0 = 0; k0 < ND; k0 += BK1) {
        #pragma unroll
        for (int p = 0; p < 4; ++p) {
            int r = p * 32 + lrow;
            float4 a = *(const float4*)(X + (size_t)(bm + r) * ND + k0 + lk);
            As[lk+0][r] = a.x; As[lk+1][r] = a.y; As[lk+2][r] = a.z; As[lk+3][r] = a.w;
            float4 b = *(const float4*)(P + (size_t)(bn + r) * ND + k0 + lk);
            Bs[lk+0][r] = b.x; Bs[lk+1][r] = b.y; Bs[lk+2][r] = b.z; Bs[lk+3][r] = b.w;
        }
        __syncthreads();
        #pragma unroll 4
        for (int k = 0; k < BK1; ++k) {
            float4 a0 = *(const float4*)&As[k][ty*8];
            float4 a1 = *(const float4*)&As[k][ty*8 + 4];
            float4 b0 = *(const float4*)&Bs[k][tx*4];
            float4 b1 = *(const float4*)&Bs[k][64 + tx*4];
            float av[8] = {a0.x,a0.y,a0.z,a0.w,a1.x,a1.y,a1.z,a1.w};
            float bv[8] = {b0.x,b0.y,b0.z,b0.w,b1.x,b1.y,b1.z,b1.w};
            #pragma unroll
            for (int i = 0; i < 8; ++i)
                #pragma unroll
                for (int j = 0; j < 8; ++j)
                    acc[i][j] = fmaf(av[i], bv[j], acc[i][j]);
        }
        __syncthreads();
    }
    unsigned long long (*red)[16] = (unsigned long long (*)[16])smem_raw;
    float cj[8];
    int   jglob[8];
    #pragma unroll
    for (int j = 0; j < 8; ++j) {
        int c = (j < 4) ? (tx*4 + j) : (64 + tx*4 + (j - 4));
        jglob[j] = bn + c;
        cj[j]    = psq[bn + c];
    }
    #pragma unroll
    for (int i = 0; i < 8; ++i) {
        float best = 0.f; unsigned bidx = 0u; bool first = true;
        #pragma unroll
        for (int j = 0; j < 8; ++j) {
            float s = fmaf(-2.f, acc[i][j], cj[j]);
            if (first || s < best) { best = s; bidx = (unsigned)jglob[j]; first = false; }
        }
        unsigned u = fkey(best);
        red[ty*8 + i][tx] = ((unsigned long long)u << 32) | (unsigned long long)bidx;
    }
    __syncthreads();
    if (tid < BM1) {
        unsigned long long m = red[tid][0];
        #pragma unroll
        for (int t = 1; t < 16; ++t) m = umin64(m, red[tid][t]);
        atomicMin(&minpack[bm + tid], m);
    }
}

__global__ void gather_kernel(const float* __restrict__ P,
                              const unsigned long long* __restrict__ minpack,
                              float* __restrict__ out) {
    int row = blockIdx.x;
    unsigned idx = (unsigned)(minpack[row] & 0xFFFFFFFFull);
    int lane = threadIdx.x;
    ((float4*)(out + (size_t)row * ND))[lane] =
        ((const float4*)(P + (size_t)idx * ND))[lane];
}

// ------------------------------------------------------------------- launch
extern "C" void kernel_launch(void* const* d_in, const int* in_sizes, int n_in,
                              void* d_out, int out_size, void* d_ws, size_t ws_size,
                              hipStream_t stream) {
    const float* X = (const float*)d_in[0];
    const float* P = (const float*)d_in[1];
    float* out = (float*)d_out;
    char* w = (char*)d_ws;

    if (ws_size >= WS_NEED) {
        float* psq = (float*)(w + OFF_PSQ);
        __bf16* Xb = (__bf16*)(w + OFF_XB);
        __bf16* Pb = (__bf16*)(w + OFF_PB);
        unsigned* blockmin = (unsigned*)(w + OFF_BM);

        prep_kernel<<<(NP + NB) / 4, 256, 0, stream>>>(X, P, psq, Xb, Pb);
        nn_sweep8_kernel<<<(NB / 128) * NSPLIT, 512, 0, stream>>>(Xb, Pb, psq,
                                                                  blockmin);
        rescore_kernel<<<NB, 256, 0, stream>>>(X, P, psq, blockmin, out);
    } else {
        float* psq = (float*)w;
        unsigned long long* minpack = (unsigned long long*)(w + (size_t)NP * 4);
        psq_init_kernel<<<NP / 4, 256, 0, stream>>>(P, psq, minpack);
        dim3 grid(NP / BN1, NB / BM1);
        nn_main_kernel<<<grid, dim3(256), 0, stream>>>(X, P, psq, minpack);
        gather_kernel<<<NB, 64, 0, stream>>>(P, minpack, out);
    }
}